// Round 1
// baseline (361.980 us; speedup 1.0000x reference)
//
#include <hip/hip_runtime.h>

#define B_ 16
#define T_ 12
#define N_ 512
#define D_ 128
#define E_ 32

// ---------------------------------------------------------------------------
// A1: qk = emb @ W_qk + b_qk  (store raw qk)  and  q = softmax(qk, axis=D)
// grid: T*N blocks, 128 threads (one per d)
// ---------------------------------------------------------------------------
__global__ __launch_bounds__(128) void kA1(const float* __restrict__ emb,
                                           const float* __restrict__ Wqk,
                                           const float* __restrict__ bqk,
                                           float* __restrict__ qk,
                                           float* __restrict__ q) {
    int tn = blockIdx.x;
    int d  = threadIdx.x;
    __shared__ float es[E_];
    if (d < E_) es[d] = emb[tn * E_ + d];
    __syncthreads();
    float acc = bqk[d];
#pragma unroll
    for (int e = 0; e < E_; ++e) acc = fmaf(es[e], Wqk[e * D_ + d], acc);
    qk[(size_t)tn * D_ + d] = acc;

    __shared__ float red[D_];
    red[d] = acc;
    __syncthreads();
#pragma unroll
    for (int s = 64; s > 0; s >>= 1) {
        if (d < s) red[d] = fmaxf(red[d], red[d + s]);
        __syncthreads();
    }
    float mx = red[0];
    __syncthreads();
    float ex = __expf(acc - mx);
    red[d] = ex;
    __syncthreads();
#pragma unroll
    for (int s = 64; s > 0; s >>= 1) {
        if (d < s) red[d] += red[d + s];
        __syncthreads();
    }
    q[(size_t)tn * D_ + d] = ex / red[0];
}

// ---------------------------------------------------------------------------
// A2: kT[t,d,n] = softmax over n of qk[t,n,d]
// grid: T*D blocks, 512 threads (one per n)
// ---------------------------------------------------------------------------
__global__ __launch_bounds__(512) void kA2(const float* __restrict__ qk,
                                           float* __restrict__ kT) {
    int t = blockIdx.x >> 7;
    int d = blockIdx.x & 127;
    int n = threadIdx.x;
    float x = qk[((size_t)t * N_ + n) * D_ + d];
    __shared__ float red[N_];
    red[n] = x;
    __syncthreads();
    for (int s = 256; s > 0; s >>= 1) {
        if (n < s) red[n] = fmaxf(red[n], red[n + s]);
        __syncthreads();
    }
    float mx = red[0];
    __syncthreads();
    float ex = __expf(x - mx);
    red[n] = ex;
    __syncthreads();
    for (int s = 256; s > 0; s >>= 1) {
        if (n < s) red[n] += red[n + s];
        __syncthreads();
    }
    kT[((size_t)t * D_ + d) * N_ + n] = ex / red[0];
}

// ---------------------------------------------------------------------------
// A3: score0[t,n,m] = sum_d q[t,n,d] * kT[t,d,m]
// grid: (mtile=8, ntile=8, t=12), 256 threads, 64x64 tile, K=128
// ---------------------------------------------------------------------------
__global__ __launch_bounds__(256) void kA3(const float* __restrict__ q,
                                           const float* __restrict__ kT,
                                           float* __restrict__ sc) {
    int mt = blockIdx.x, nt = blockIdx.y, t = blockIdx.z;
    int n0 = nt * 64, m0 = mt * 64;
    int tid = threadIdx.x;
    int tx = tid & 15, ty = tid >> 4;  // 16x16 threads, 4x4 micro-tile

    __shared__ float Qs[64 * 132];  // LD 132: float4-aligned, 2-way max conflict
    __shared__ float Ks[128 * 64];

    const float* qt = q + (size_t)t * N_ * D_;
    const float* kt = kT + (size_t)t * D_ * N_;

    for (int idx = tid; idx < 64 * 32; idx += 256) {
        int r = idx >> 5, c4 = idx & 31;
        *(float4*)&Qs[r * 132 + c4 * 4] =
            *(const float4*)&qt[(size_t)(n0 + r) * D_ + c4 * 4];
    }
    for (int idx = tid; idx < 128 * 16; idx += 256) {
        int r = idx >> 4, c4 = idx & 15;
        *(float4*)&Ks[r * 64 + c4 * 4] =
            *(const float4*)&kt[(size_t)r * N_ + m0 + c4 * 4];
    }
    __syncthreads();

    float acc[4][4] = {};
    for (int k = 0; k < 128; k += 4) {
        float4 av[4];
#pragma unroll
        for (int i = 0; i < 4; ++i)
            av[i] = *(const float4*)&Qs[(ty * 4 + i) * 132 + k];
#pragma unroll
        for (int kk = 0; kk < 4; ++kk) {
            float4 bv = *(const float4*)&Ks[(k + kk) * 64 + tx * 4];
#pragma unroll
            for (int i = 0; i < 4; ++i) {
                float a = kk == 0 ? av[i].x : kk == 1 ? av[i].y
                         : kk == 2 ? av[i].z : av[i].w;
                acc[i][0] = fmaf(a, bv.x, acc[i][0]);
                acc[i][1] = fmaf(a, bv.y, acc[i][1]);
                acc[i][2] = fmaf(a, bv.z, acc[i][2]);
                acc[i][3] = fmaf(a, bv.w, acc[i][3]);
            }
        }
    }
    float* st = sc + (size_t)t * N_ * N_;
#pragma unroll
    for (int i = 0; i < 4; ++i) {
        *(float4*)&st[(size_t)(n0 + ty * 4 + i) * N_ + m0 + tx * 4] =
            make_float4(acc[i][0], acc[i][1], acc[i][2], acc[i][3]);
    }
}

// ---------------------------------------------------------------------------
// B: v = value @ W_v + b_v   (rows = B*T*N, K = D = 128)
// grid: B*T*N/64 blocks, 256 threads, tile 64 rows x 128 cols, K-chunk 32
// ---------------------------------------------------------------------------
__global__ __launch_bounds__(256) void kB(const float* __restrict__ value,
                                          const float* __restrict__ Wv,
                                          const float* __restrict__ bv,
                                          float* __restrict__ v) {
    int g0 = blockIdx.x * 64;
    int tid = threadIdx.x;
    int tx = tid & 31, ty = tid >> 5;  // cols tx*4..+3, rows ty*8..+7

    __shared__ float Vs[64 * 36];   // padded LD 36
    __shared__ float Ws[32 * 128];

    float acc[8][4] = {};
    for (int kc = 0; kc < 4; ++kc) {
        __syncthreads();
        for (int idx = tid; idx < 64 * 8; idx += 256) {
            int r = idx >> 3, c4 = idx & 7;
            *(float4*)&Vs[r * 36 + c4 * 4] =
                *(const float4*)&value[(size_t)(g0 + r) * D_ + kc * 32 + c4 * 4];
        }
        for (int idx = tid; idx < 32 * 32; idx += 256) {
            int r = idx >> 5, c4 = idx & 31;
            *(float4*)&Ws[r * 128 + c4 * 4] =
                *(const float4*)&Wv[(size_t)(kc * 32 + r) * D_ + c4 * 4];
        }
        __syncthreads();
#pragma unroll
        for (int k = 0; k < 32; k += 4) {
            float4 av[8];
#pragma unroll
            for (int i = 0; i < 8; ++i)
                av[i] = *(const float4*)&Vs[(ty * 8 + i) * 36 + k];
#pragma unroll
            for (int kk = 0; kk < 4; ++kk) {
                float4 bw = *(const float4*)&Ws[(k + kk) * 128 + tx * 4];
#pragma unroll
                for (int i = 0; i < 8; ++i) {
                    float a = kk == 0 ? av[i].x : kk == 1 ? av[i].y
                             : kk == 2 ? av[i].z : av[i].w;
                    acc[i][0] = fmaf(a, bw.x, acc[i][0]);
                    acc[i][1] = fmaf(a, bw.y, acc[i][1]);
                    acc[i][2] = fmaf(a, bw.z, acc[i][2]);
                    acc[i][3] = fmaf(a, bw.w, acc[i][3]);
                }
            }
        }
    }
    float4 bias = *(const float4*)&bv[tx * 4];
#pragma unroll
    for (int i = 0; i < 8; ++i) {
        *(float4*)&v[(size_t)(g0 + ty * 8 + i) * D_ + tx * 4] =
            make_float4(acc[i][0] + bias.x, acc[i][1] + bias.y,
                        acc[i][2] + bias.z, acc[i][3] + bias.w);
    }
}

// ---------------------------------------------------------------------------
// C: out[b,t,n,d] = sum_m (mask[b,n,m] ? score0[t,n,m] : -1e9) * v[b,t,m,d]
// grid: (ntile=8, t=12, b=16), 256 threads, tile 64(n) x 128(d), K=512 over m
// ---------------------------------------------------------------------------
__global__ __launch_bounds__(256) void kC(const float* __restrict__ sc,
                                          const int* __restrict__ mask,
                                          const float* __restrict__ v,
                                          float* __restrict__ out) {
    int nt = blockIdx.x, t = blockIdx.y, b = blockIdx.z;
    int n0 = nt * 64;
    int tid = threadIdx.x;
    int tx = tid & 31, ty = tid >> 5;

    const float* st  = sc + (size_t)t * N_ * N_;
    const float* vbt = v + ((size_t)(b * T_ + t)) * N_ * D_;
    const int*   mb  = mask + (size_t)b * N_ * N_;
    float*       ob  = out + ((size_t)(b * T_ + t)) * N_ * D_;

    __shared__ float Ss[64 * 36];   // padded LD 36
    __shared__ float Vs[32 * 128];

    float acc[8][4] = {};
    for (int mc = 0; mc < 16; ++mc) {
        int m0 = mc * 32;
        __syncthreads();
        for (int idx = tid; idx < 64 * 8; idx += 256) {
            int r = idx >> 3, c4 = idx & 7;
            size_t g = (size_t)(n0 + r) * N_ + m0 + c4 * 4;
            float4 s4 = *(const float4*)&st[g];
            int4   m4 = *(const int4*)&mb[g];
            float4 o;
            o.x = m4.x ? s4.x : -1e9f;
            o.y = m4.y ? s4.y : -1e9f;
            o.z = m4.z ? s4.z : -1e9f;
            o.w = m4.w ? s4.w : -1e9f;
            *(float4*)&Ss[r * 36 + c4 * 4] = o;
        }
        for (int idx = tid; idx < 32 * 32; idx += 256) {
            int r = idx >> 5, c4 = idx & 31;
            *(float4*)&Vs[r * 128 + c4 * 4] =
                *(const float4*)&vbt[(size_t)(m0 + r) * D_ + c4 * 4];
        }
        __syncthreads();
#pragma unroll
        for (int k = 0; k < 32; k += 4) {
            float4 av[8];
#pragma unroll
            for (int i = 0; i < 8; ++i)
                av[i] = *(const float4*)&Ss[(ty * 8 + i) * 36 + k];
#pragma unroll
            for (int kk = 0; kk < 4; ++kk) {
                float4 bv = *(const float4*)&Vs[(k + kk) * 128 + tx * 4];
#pragma unroll
                for (int i = 0; i < 8; ++i) {
                    float a = kk == 0 ? av[i].x : kk == 1 ? av[i].y
                             : kk == 2 ? av[i].z : av[i].w;
                    acc[i][0] = fmaf(a, bv.x, acc[i][0]);
                    acc[i][1] = fmaf(a, bv.y, acc[i][1]);
                    acc[i][2] = fmaf(a, bv.z, acc[i][2]);
                    acc[i][3] = fmaf(a, bv.w, acc[i][3]);
                }
            }
        }
    }
#pragma unroll
    for (int i = 0; i < 8; ++i) {
        *(float4*)&ob[(size_t)(n0 + ty * 8 + i) * D_ + tx * 4] =
            make_float4(acc[i][0], acc[i][1], acc[i][2], acc[i][3]);
    }
}

// ---------------------------------------------------------------------------
extern "C" void kernel_launch(void* const* d_in, const int* in_sizes, int n_in,
                              void* d_out, int out_size, void* d_ws, size_t ws_size,
                              hipStream_t stream) {
    const float* value = (const float*)d_in[0];  // [B,T,N,D]
    const float* emb   = (const float*)d_in[1];  // [T,N,E]
    const int*   mask  = (const int*)d_in[2];    // [B,N,N]
    const float* Wqk   = (const float*)d_in[3];  // [E,D]
    const float* bqk   = (const float*)d_in[4];  // [D]
    const float* Wv    = (const float*)d_in[5];  // [D,D]
    const float* bvv   = (const float*)d_in[6];  // [D]
    float* out = (float*)d_out;

    float* ws = (float*)d_ws;
    float* q  = ws;                    // T*N*D   = 786432
    float* kT = ws + 786432;           // T*D*N   = 786432
    float* sc = ws + 1572864;          // T*N*N   = 3145728 (first part = qk temp)
    float* qk = sc;
    float* v  = ws + 4718592;          // B*T*N*D = 12582912

    kA1<<<T_ * N_, 128, 0, stream>>>(emb, Wqk, bqk, qk, q);
    kA2<<<T_ * D_, 512, 0, stream>>>(qk, kT);
    kA3<<<dim3(8, 8, T_), 256, 0, stream>>>(q, kT, sc);
    kB<<<(B_ * T_ * N_) / 64, 256, 0, stream>>>(value, Wv, bvv, v);
    kC<<<dim3(8, T_, B_), 256, 0, stream>>>(sc, mask, v, out);
}

// Round 3
// 231.360 us; speedup vs baseline: 1.5646x; 1.5646x over previous
//
#include <hip/hip_runtime.h>

#define B_ 16
#define T_ 12
#define N_ 512
#define D_ 128
#define E_ 32

typedef __attribute__((ext_vector_type(8))) unsigned short u16x8;
typedef __attribute__((ext_vector_type(8))) __bf16 bf16x8;
typedef __attribute__((ext_vector_type(4))) float f32x4;

static __device__ __forceinline__ unsigned short f2bf(float f) {
    unsigned u = __float_as_uint(f);
    unsigned r = (u + 0x7fffu + ((u >> 16) & 1u)) >> 16;
    return (unsigned short)r;
}

// ---------------------------------------------------------------------------
// A1: qk = emb @ W_qk + b_qk  (store raw qk)  and  q = softmax(qk, axis=D)
// ---------------------------------------------------------------------------
__global__ __launch_bounds__(128) void kA1(const float* __restrict__ emb,
                                           const float* __restrict__ Wqk,
                                           const float* __restrict__ bqk,
                                           float* __restrict__ qk,
                                           float* __restrict__ q) {
    int tn = blockIdx.x;
    int d  = threadIdx.x;
    __shared__ float es[E_];
    if (d < E_) es[d] = emb[tn * E_ + d];
    __syncthreads();
    float acc = bqk[d];
#pragma unroll
    for (int e = 0; e < E_; ++e) acc = fmaf(es[e], Wqk[e * D_ + d], acc);
    qk[(size_t)tn * D_ + d] = acc;

    __shared__ float red[D_];
    red[d] = acc;
    __syncthreads();
#pragma unroll
    for (int s = 64; s > 0; s >>= 1) {
        if (d < s) red[d] = fmaxf(red[d], red[d + s]);
        __syncthreads();
    }
    float mx = red[0];
    __syncthreads();
    float ex = __expf(acc - mx);
    red[d] = ex;
    __syncthreads();
#pragma unroll
    for (int s = 64; s > 0; s >>= 1) {
        if (d < s) red[d] += red[d + s];
        __syncthreads();
    }
    q[(size_t)tn * D_ + d] = ex / red[0];
}

// ---------------------------------------------------------------------------
// A2: kT[t,d,n] = softmax over n of qk[t,n,d]
// ---------------------------------------------------------------------------
__global__ __launch_bounds__(512) void kA2(const float* __restrict__ qk,
                                           float* __restrict__ kT) {
    int t = blockIdx.x >> 7;
    int d = blockIdx.x & 127;
    int n = threadIdx.x;
    float x = qk[((size_t)t * N_ + n) * D_ + d];
    __shared__ float red[N_];
    red[n] = x;
    __syncthreads();
    for (int s = 256; s > 0; s >>= 1) {
        if (n < s) red[n] = fmaxf(red[n], red[n + s]);
        __syncthreads();
    }
    float mx = red[0];
    __syncthreads();
    float ex = __expf(x - mx);
    red[n] = ex;
    __syncthreads();
    for (int s = 256; s > 0; s >>= 1) {
        if (n < s) red[n] += red[n + s];
        __syncthreads();
    }
    kT[((size_t)t * D_ + d) * N_ + n] = ex / red[0];
}

// ---------------------------------------------------------------------------
// A3: score0[t,n,m] = sum_d q[t,n,d] * kT[t,d,m]  -> bf16 output
// ---------------------------------------------------------------------------
__global__ __launch_bounds__(256) void kA3(const float* __restrict__ q,
                                           const float* __restrict__ kT,
                                           unsigned short* __restrict__ sc) {
    int mt = blockIdx.x, nt = blockIdx.y, t = blockIdx.z;
    int n0 = nt * 64, m0 = mt * 64;
    int tid = threadIdx.x;
    int tx = tid & 15, ty = tid >> 4;

    __shared__ float Qs[64 * 132];
    __shared__ float Ks[128 * 64];

    const float* qt = q + (size_t)t * N_ * D_;
    const float* kt = kT + (size_t)t * D_ * N_;

    for (int idx = tid; idx < 64 * 32; idx += 256) {
        int r = idx >> 5, c4 = idx & 31;
        *(float4*)&Qs[r * 132 + c4 * 4] =
            *(const float4*)&qt[(size_t)(n0 + r) * D_ + c4 * 4];
    }
    for (int idx = tid; idx < 128 * 16; idx += 256) {
        int r = idx >> 4, c4 = idx & 15;
        *(float4*)&Ks[r * 64 + c4 * 4] =
            *(const float4*)&kt[(size_t)r * N_ + m0 + c4 * 4];
    }
    __syncthreads();

    float acc[4][4] = {};
    for (int k = 0; k < 128; k += 4) {
        float4 av[4];
#pragma unroll
        for (int i = 0; i < 4; ++i)
            av[i] = *(const float4*)&Qs[(ty * 4 + i) * 132 + k];
#pragma unroll
        for (int kk = 0; kk < 4; ++kk) {
            float4 bv = *(const float4*)&Ks[(k + kk) * 64 + tx * 4];
#pragma unroll
            for (int i = 0; i < 4; ++i) {
                float a = kk == 0 ? av[i].x : kk == 1 ? av[i].y
                         : kk == 2 ? av[i].z : av[i].w;
                acc[i][0] = fmaf(a, bv.x, acc[i][0]);
                acc[i][1] = fmaf(a, bv.y, acc[i][1]);
                acc[i][2] = fmaf(a, bv.z, acc[i][2]);
                acc[i][3] = fmaf(a, bv.w, acc[i][3]);
            }
        }
    }
    unsigned short* st = sc + (size_t)t * N_ * N_;
#pragma unroll
    for (int i = 0; i < 4; ++i) {
        ushort4 o;
        o.x = f2bf(acc[i][0]); o.y = f2bf(acc[i][1]);
        o.z = f2bf(acc[i][2]); o.w = f2bf(acc[i][3]);
        *(ushort4*)&st[(size_t)(n0 + ty * 4 + i) * N_ + m0 + tx * 4] = o;
    }
}

// ---------------------------------------------------------------------------
// kM: pack mask[b,n,m] (int 0/1) into bitmask words: mb[(b*512+n)*16 + m/32]
// ---------------------------------------------------------------------------
__global__ __launch_bounds__(256) void kM(const int* __restrict__ mask,
                                          unsigned* __restrict__ mb) {
    int o = blockIdx.x * 256 + threadIdx.x;  // 0..131071
    const int* mp = mask + (size_t)o * 32;
    unsigned bits = 0;
#pragma unroll
    for (int j = 0; j < 32; j += 4) {
        int4 m4 = *(const int4*)&mp[j];
        bits |= (m4.x ? 1u : 0u) << j;
        bits |= (m4.y ? 1u : 0u) << (j + 1);
        bits |= (m4.z ? 1u : 0u) << (j + 2);
        bits |= (m4.w ? 1u : 0u) << (j + 3);
    }
    mb[o] = bits;
}

// ---------------------------------------------------------------------------
// B: v = value @ W_v + b_v  (fp32 compute, bf16 store)
// ---------------------------------------------------------------------------
__global__ __launch_bounds__(256) void kB(const float* __restrict__ value,
                                          const float* __restrict__ Wv,
                                          const float* __restrict__ bv,
                                          unsigned short* __restrict__ v) {
    int g0 = blockIdx.x * 64;
    int tid = threadIdx.x;
    int tx = tid & 31, ty = tid >> 5;

    __shared__ float Vs[64 * 36];
    __shared__ float Ws[32 * 128];

    float acc[8][4] = {};
    for (int kc = 0; kc < 4; ++kc) {
        __syncthreads();
        for (int idx = tid; idx < 64 * 8; idx += 256) {
            int r = idx >> 3, c4 = idx & 7;
            *(float4*)&Vs[r * 36 + c4 * 4] =
                *(const float4*)&value[(size_t)(g0 + r) * D_ + kc * 32 + c4 * 4];
        }
        for (int idx = tid; idx < 32 * 32; idx += 256) {
            int r = idx >> 5, c4 = idx & 31;
            *(float4*)&Ws[r * 128 + c4 * 4] =
                *(const float4*)&Wv[(size_t)(kc * 32 + r) * D_ + c4 * 4];
        }
        __syncthreads();
#pragma unroll
        for (int k = 0; k < 32; k += 4) {
            float4 av[8];
#pragma unroll
            for (int i = 0; i < 8; ++i)
                av[i] = *(const float4*)&Vs[(ty * 8 + i) * 36 + k];
#pragma unroll
            for (int kk = 0; kk < 4; ++kk) {
                float4 bw = *(const float4*)&Ws[(k + kk) * 128 + tx * 4];
#pragma unroll
                for (int i = 0; i < 8; ++i) {
                    float a = kk == 0 ? av[i].x : kk == 1 ? av[i].y
                             : kk == 2 ? av[i].z : av[i].w;
                    acc[i][0] = fmaf(a, bw.x, acc[i][0]);
                    acc[i][1] = fmaf(a, bw.y, acc[i][1]);
                    acc[i][2] = fmaf(a, bw.z, acc[i][2]);
                    acc[i][3] = fmaf(a, bw.w, acc[i][3]);
                }
            }
        }
    }
    float4 bias = *(const float4*)&bv[tx * 4];
#pragma unroll
    for (int i = 0; i < 8; ++i) {
        ushort4 o;
        o.x = f2bf(acc[i][0] + bias.x);
        o.y = f2bf(acc[i][1] + bias.y);
        o.z = f2bf(acc[i][2] + bias.z);
        o.w = f2bf(acc[i][3] + bias.w);
        *(ushort4*)&v[(size_t)(g0 + ty * 8 + i) * D_ + tx * 4] = o;
    }
}

// ---------------------------------------------------------------------------
// kTr: vT[bt, d, m] = v[bt, m, d]   (bf16, per (b,t) 64(m)x128(d) tile)
// grid: (8 m-tiles, 192 bt), 256 threads
// ---------------------------------------------------------------------------
__global__ __launch_bounds__(256) void kTr(const unsigned short* __restrict__ v,
                                           unsigned short* __restrict__ vt) {
    int mt = blockIdx.x, bt = blockIdx.y;
    const unsigned short* vp = v + (size_t)bt * 65536 + (size_t)mt * 64 * 128;
    unsigned short* op = vt + (size_t)bt * 65536 + mt * 64;
    __shared__ unsigned short Ls[64 * 136];
    int tid = threadIdx.x;
    // load full 64(m) x 128(d) tile: 1024 u16x8 vectors
#pragma unroll
    for (int i = 0; i < 4; ++i) {
        int lin = tid + i * 256;           // 0..1023
        int r = lin >> 4, seg = lin & 15;  // r: m-row 0..63, seg: 8-col group 0..15
        *(u16x8*)&Ls[r * 136 + seg * 8] = *(const u16x8*)&vp[r * 128 + seg * 8];
    }
    __syncthreads();
#pragma unroll
    for (int i = 0; i < 2; ++i) {
        int lin = tid + i * 256;           // 0..511
        int d = lin >> 2, ms = lin & 3;
        unsigned short tmp[16];
#pragma unroll
        for (int j = 0; j < 16; ++j) tmp[j] = Ls[(ms * 16 + j) * 136 + d];
        *(u16x8*)&op[(size_t)d * 512 + ms * 16]     = *(u16x8*)&tmp[0];
        *(u16x8*)&op[(size_t)d * 512 + ms * 16 + 8] = *(u16x8*)&tmp[8];
    }
}

// ---------------------------------------------------------------------------
// kC: out[b,t,n,d] = sum_m (mask ? score0 : -1e9) * v[b,t,m,d]  via bf16 MFMA
// tile 128(n) x 128(d), K = m = 512, BK = 32. grid (4, T, B), 256 thr = 4 waves
// ---------------------------------------------------------------------------
__global__ __launch_bounds__(256) void kC(const unsigned short* __restrict__ sc,
                                          const unsigned* __restrict__ mb,
                                          const unsigned short* __restrict__ vT,
                                          float* __restrict__ out) {
    int n0 = blockIdx.x * 128;
    int t = blockIdx.y, b = blockIdx.z;
    int tid = threadIdx.x;
    int wave = tid >> 6, lane = tid & 63;
    int q = lane >> 4, lr = lane & 15;
    int rbase = (wave & 1) * 64;   // n offset within tile
    int cbase = (wave >> 1) * 64;  // d offset

    __shared__ unsigned short Ss[128 * 40];  // [n_local][k] stride 40
    __shared__ unsigned short Vs[128 * 40];  // [d][k]

    const unsigned short* scp = sc + (size_t)t * N_ * N_ + (size_t)n0 * N_;
    const unsigned short* vtp = vT + ((size_t)(b * T_ + t)) * N_ * D_;  // [d][m]
    const unsigned* mbp = mb + ((size_t)b * N_ + n0) * 16;

    const unsigned short NEG = 0xCE6E;  // bf16(-1e9)

    f32x4 acc[4][4];
#pragma unroll
    for (int i = 0; i < 4; ++i)
#pragma unroll
        for (int j = 0; j < 4; ++j) acc[i][j] = (f32x4){0.f, 0.f, 0.f, 0.f};

    int sr = tid >> 1, sh = tid & 1;  // S staging: row, half

    for (int kc = 0; kc < 16; ++kc) {
        int m0 = kc * 32;
        // --- stage S (masked score -> bf16) ---
        const unsigned short* g = scp + (size_t)sr * N_ + m0 + sh * 16;
        u16x8 s0 = *(const u16x8*)g;
        u16x8 s1 = *(const u16x8*)(g + 8);
        unsigned bits = mbp[sr * 16 + kc] >> (sh * 16);
        u16x8 o0, o1;
#pragma unroll
        for (int j = 0; j < 8; ++j) {
            o0[j] = ((bits >> j) & 1u) ? s0[j] : NEG;
            o1[j] = ((bits >> (j + 8)) & 1u) ? s1[j] : NEG;
        }
        *(u16x8*)&Ss[sr * 40 + sh * 16]     = o0;
        *(u16x8*)&Ss[sr * 40 + sh * 16 + 8] = o1;
        // --- stage V ---
#pragma unroll
        for (int i = 0; i < 2; ++i) {
            int lin = tid + i * 256;        // 0..511
            int d = lin >> 2, qq = lin & 3;
            *(u16x8*)&Vs[d * 40 + qq * 8] =
                *(const u16x8*)&vtp[(size_t)d * N_ + m0 + qq * 8];
        }
        __syncthreads();
        // --- compute ---
        bf16x8 a[4], bfr[4];
#pragma unroll
        for (int i = 0; i < 4; ++i)
            a[i] = *(const bf16x8*)&Ss[(rbase + 16 * i + lr) * 40 + q * 8];
#pragma unroll
        for (int j = 0; j < 4; ++j)
            bfr[j] = *(const bf16x8*)&Vs[(cbase + 16 * j + lr) * 40 + q * 8];
#pragma unroll
        for (int i = 0; i < 4; ++i)
#pragma unroll
            for (int j = 0; j < 4; ++j)
                acc[i][j] = __builtin_amdgcn_mfma_f32_16x16x32_bf16(
                    a[i], bfr[j], acc[i][j], 0, 0, 0);
        __syncthreads();
    }

    // epilogue: C/D layout col = lane&15, row = q*4 + reg
    float* ob = out + ((size_t)(b * T_ + t)) * N_ * D_;
#pragma unroll
    for (int i = 0; i < 4; ++i) {
#pragma unroll
        for (int j = 0; j < 4; ++j) {
            int row0 = n0 + rbase + 16 * i + q * 4;
            int col = cbase + 16 * j + lr;
#pragma unroll
            for (int e = 0; e < 4; ++e)
                ob[(size_t)(row0 + e) * D_ + col] = acc[i][j][e];
        }
    }
}

// ---------------------------------------------------------------------------
extern "C" void kernel_launch(void* const* d_in, const int* in_sizes, int n_in,
                              void* d_out, int out_size, void* d_ws, size_t ws_size,
                              hipStream_t stream) {
    const float* value = (const float*)d_in[0];
    const float* emb   = (const float*)d_in[1];
    const int*   mask  = (const int*)d_in[2];
    const float* Wqk   = (const float*)d_in[3];
    const float* bqk   = (const float*)d_in[4];
    const float* Wv    = (const float*)d_in[5];
    const float* bvv   = (const float*)d_in[6];
    float* out = (float*)d_out;

    float* ws = (float*)d_ws;
    float* qf  = ws;                                   // 786432 f
    float* kTf = ws + 786432;                          // 786432 f
    float* qkf = ws + 1572864;                         // 786432 f
    unsigned short* scb = (unsigned short*)(ws + 2359296);   // 3145728 ush
    unsigned short* vb  = (unsigned short*)(ws + 3932160);   // 12582912 ush
    unsigned short* vtb = (unsigned short*)(ws + 10223616);  // 12582912 ush
    unsigned* mbp       = (unsigned*)(ws + 16515072);        // 131072 u32

    kA1<<<T_ * N_, 128, 0, stream>>>(emb, Wqk, bqk, qkf, qf);
    kA2<<<T_ * D_, 512, 0, stream>>>(qkf, kTf);
    kA3<<<dim3(8, 8, T_), 256, 0, stream>>>(qf, kTf, scb);
    kM<<<512, 256, 0, stream>>>(mask, mbp);
    kB<<<(B_ * T_ * N_) / 64, 256, 0, stream>>>(value, Wv, bvv, vb);
    kTr<<<dim3(8, B_ * T_), 256, 0, stream>>>(vb, vtb);
    kC<<<dim3(4, T_, B_), 256, 0, stream>>>(scb, mbp, vtb, out);
}

// Round 4
// 178.144 us; speedup vs baseline: 2.0320x; 1.2987x over previous
//
#include <hip/hip_runtime.h>

#define B_ 16
#define T_ 12
#define N_ 512
#define D_ 128
#define E_ 32

typedef __attribute__((ext_vector_type(8))) unsigned short u16x8;
typedef __attribute__((ext_vector_type(8))) __bf16 bf16x8;
typedef __attribute__((ext_vector_type(4))) float f32x4;

static __device__ __forceinline__ unsigned short f2bf(float f) {
    unsigned u = __float_as_uint(f);
    unsigned r = (u + 0x7fffu + ((u >> 16) & 1u)) >> 16;
    return (unsigned short)r;
}

// ---------------------------------------------------------------------------
// A1: qk = emb @ W_qk + b_qk (fp32 store) and q = softmax(qk, axis=D) -> bf16
// ---------------------------------------------------------------------------
__global__ __launch_bounds__(128) void kA1(const float* __restrict__ emb,
                                           const float* __restrict__ Wqk,
                                           const float* __restrict__ bqk,
                                           float* __restrict__ qk,
                                           unsigned short* __restrict__ qb) {
    int tn = blockIdx.x;
    int d  = threadIdx.x;
    __shared__ float es[E_];
    if (d < E_) es[d] = emb[tn * E_ + d];
    __syncthreads();
    float acc = bqk[d];
#pragma unroll
    for (int e = 0; e < E_; ++e) acc = fmaf(es[e], Wqk[e * D_ + d], acc);
    qk[(size_t)tn * D_ + d] = acc;

    __shared__ float red[D_];
    red[d] = acc;
    __syncthreads();
#pragma unroll
    for (int s = 64; s > 0; s >>= 1) {
        if (d < s) red[d] = fmaxf(red[d], red[d + s]);
        __syncthreads();
    }
    float mx = red[0];
    __syncthreads();
    float ex = __expf(acc - mx);
    red[d] = ex;
    __syncthreads();
#pragma unroll
    for (int s = 64; s > 0; s >>= 1) {
        if (d < s) red[d] += red[d + s];
        __syncthreads();
    }
    qb[(size_t)tn * D_ + d] = f2bf(ex / red[0]);
}

// ---------------------------------------------------------------------------
// A2n: kN[t,n,d] = softmax over n of qk[t,n,d], KEPT in [n][d] layout, bf16.
// grid: (t=12, dtile=4) -> 48 blocks, 256 thr = 8(ni) x 32(dc); 64 n/thread.
// ---------------------------------------------------------------------------
__global__ __launch_bounds__(256) void kA2n(const float* __restrict__ qk,
                                            unsigned short* __restrict__ kN) {
    int t = blockIdx.x >> 2;
    int d0 = (blockIdx.x & 3) * 32;
    int tid = threadIdx.x;
    int dc = tid & 31, ni = tid >> 5;
    const float* base = qk + (size_t)t * N_ * D_ + d0 + dc;
    float vals[64];
    float mx = -1e30f;
#pragma unroll
    for (int j = 0; j < 64; ++j) {
        vals[j] = base[(size_t)(ni + 8 * j) * D_];
        mx = fmaxf(mx, vals[j]);
    }
    __shared__ float red[8][33];
    red[ni][dc] = mx;
    __syncthreads();
    if (ni == 0) {
        float m = red[0][dc];
#pragma unroll
        for (int r = 1; r < 8; ++r) m = fmaxf(m, red[r][dc]);
        red[0][dc] = m;
    }
    __syncthreads();
    mx = red[0][dc];
    float sum = 0.f;
#pragma unroll
    for (int j = 0; j < 64; ++j) {
        vals[j] = __expf(vals[j] - mx);
        sum += vals[j];
    }
    __syncthreads();
    red[ni][dc] = sum;
    __syncthreads();
    if (ni == 0) {
        float s = red[0][dc];
#pragma unroll
        for (int r = 1; r < 8; ++r) s += red[r][dc];
        red[0][dc] = s;
    }
    __syncthreads();
    float inv = 1.f / red[0][dc];
    unsigned short* op = kN + (size_t)t * N_ * D_ + d0 + dc;
#pragma unroll
    for (int j = 0; j < 64; ++j)
        op[(size_t)(ni + 8 * j) * D_] = f2bf(vals[j] * inv);
}

// ---------------------------------------------------------------------------
// kW: WvT[d][k] = bf16(Wv[k][d])  (128x128, trivial)
// ---------------------------------------------------------------------------
__global__ __launch_bounds__(256) void kW(const float* __restrict__ Wv,
                                          unsigned short* __restrict__ WvT) {
    int i = blockIdx.x * 256 + threadIdx.x;  // 0..16383
    int d = i >> 7, k = i & 127;
    WvT[d * 128 + k] = f2bf(Wv[k * 128 + d]);
}

// ---------------------------------------------------------------------------
// A3m: sc[t,n,m] = sum_d qb[t,n,d] * kN[t,m,d]  via bf16 MFMA -> bf16 out
// tile 128(n) x 128(m), K=128 in 2 chunks of 64. grid (4,4,12), 4 waves.
// ---------------------------------------------------------------------------
__global__ __launch_bounds__(256) void kA3m(const unsigned short* __restrict__ qb,
                                            const unsigned short* __restrict__ kN,
                                            unsigned short* __restrict__ sc) {
    int mt = blockIdx.x, nt = blockIdx.y, t = blockIdx.z;
    int n0 = nt * 128, m0 = mt * 128;
    int tid = threadIdx.x;
    int wave = tid >> 6, lane = tid & 63;
    int q = lane >> 4, lr = lane & 15;
    int rbase = (wave & 1) * 64, cbase = (wave >> 1) * 64;

    __shared__ unsigned short Qs[128 * 72];
    __shared__ unsigned short Ks[128 * 72];

    const unsigned short* qp = qb + (size_t)t * N_ * D_ + (size_t)n0 * D_;
    const unsigned short* kp = kN + (size_t)t * N_ * D_ + (size_t)m0 * D_;

    f32x4 acc[4][4];
#pragma unroll
    for (int i = 0; i < 4; ++i)
#pragma unroll
        for (int j = 0; j < 4; ++j) acc[i][j] = (f32x4){0.f, 0.f, 0.f, 0.f};

    for (int c = 0; c < 2; ++c) {
        int k0 = c * 64;
        __syncthreads();
#pragma unroll
        for (int i = 0; i < 4; ++i) {
            int lin = tid + i * 256;           // 0..1023
            int r = lin >> 3, seg = lin & 7;   // 128 rows x 8 segs
            *(u16x8*)&Qs[r * 72 + seg * 8] =
                *(const u16x8*)&qp[(size_t)r * D_ + k0 + seg * 8];
            *(u16x8*)&Ks[r * 72 + seg * 8] =
                *(const u16x8*)&kp[(size_t)r * D_ + k0 + seg * 8];
        }
        __syncthreads();
#pragma unroll
        for (int kk = 0; kk < 2; ++kk) {
            bf16x8 a[4], b[4];
#pragma unroll
            for (int i = 0; i < 4; ++i)
                a[i] = *(const bf16x8*)&Qs[(rbase + 16 * i + lr) * 72 + kk * 32 + q * 8];
#pragma unroll
            for (int j = 0; j < 4; ++j)
                b[j] = *(const bf16x8*)&Ks[(cbase + 16 * j + lr) * 72 + kk * 32 + q * 8];
#pragma unroll
            for (int i = 0; i < 4; ++i)
#pragma unroll
                for (int j = 0; j < 4; ++j)
                    acc[i][j] = __builtin_amdgcn_mfma_f32_16x16x32_bf16(
                        a[i], b[j], acc[i][j], 0, 0, 0);
        }
    }
    unsigned short* sp = sc + (size_t)t * N_ * N_;
#pragma unroll
    for (int i = 0; i < 4; ++i)
#pragma unroll
        for (int j = 0; j < 4; ++j) {
            int row0 = n0 + rbase + 16 * i + q * 4;
            int col = m0 + cbase + 16 * j + lr;
#pragma unroll
            for (int e = 0; e < 4; ++e)
                sp[(size_t)(row0 + e) * N_ + col] = f2bf(acc[i][j][e]);
        }
}

// ---------------------------------------------------------------------------
// kM: pack mask[b,n,m] (int 0/1) into bitmask words
// ---------------------------------------------------------------------------
__global__ __launch_bounds__(256) void kM(const int* __restrict__ mask,
                                          unsigned* __restrict__ mb) {
    int o = blockIdx.x * 256 + threadIdx.x;
    const int* mp = mask + (size_t)o * 32;
    unsigned bits = 0;
#pragma unroll
    for (int j = 0; j < 32; j += 4) {
        int4 m4 = *(const int4*)&mp[j];
        bits |= (m4.x ? 1u : 0u) << j;
        bits |= (m4.y ? 1u : 0u) << (j + 1);
        bits |= (m4.z ? 1u : 0u) << (j + 2);
        bits |= (m4.w ? 1u : 0u) << (j + 3);
    }
    mb[o] = bits;
}

// ---------------------------------------------------------------------------
// kBm: vT[bt][d][m] = sum_k Wv[k][d]*value[bt,m,k] + bv[d]  via bf16 MFMA.
// A = WvT[d][k] (bf16 global), B = value rows (fp32 -> bf16 during staging).
// Output is written DIRECTLY transposed (kTr eliminated).
// tile 128(d) x 128(m), K=128 in 2 chunks of 64. grid (4 mt, 192 bt).
// ---------------------------------------------------------------------------
__global__ __launch_bounds__(256) void kBm(const float* __restrict__ value,
                                           const unsigned short* __restrict__ WvT,
                                           const float* __restrict__ bv,
                                           unsigned short* __restrict__ vT) {
    int mt = blockIdx.x, bt = blockIdx.y;
    int m0 = mt * 128;
    int tid = threadIdx.x;
    int wave = tid >> 6, lane = tid & 63;
    int q = lane >> 4, lr = lane & 15;
    int rbase = (wave & 1) * 64, cbase = (wave >> 1) * 64;

    __shared__ unsigned short Ws[128 * 72];  // [d][k]
    __shared__ unsigned short Vs[128 * 72];  // [m][k]

    const float* vp = value + ((size_t)bt * N_ + m0) * D_;

    f32x4 acc[4][4];
#pragma unroll
    for (int i = 0; i < 4; ++i)
#pragma unroll
        for (int j = 0; j < 4; ++j) acc[i][j] = (f32x4){0.f, 0.f, 0.f, 0.f};

    for (int c = 0; c < 2; ++c) {
        int k0 = c * 64;
        __syncthreads();
#pragma unroll
        for (int i = 0; i < 4; ++i) {
            int lin = tid + i * 256;          // 0..1023
            int r = lin >> 3, seg = lin & 7;
            *(u16x8*)&Ws[r * 72 + seg * 8] =
                *(const u16x8*)&WvT[r * 128 + k0 + seg * 8];
        }
#pragma unroll
        for (int i = 0; i < 8; ++i) {
            int lin = tid + i * 256;          // 0..2047 float4s
            int r = lin >> 4, c4 = lin & 15;  // 128 rows x 16 float4
            float4 f = *(const float4*)&vp[(size_t)r * D_ + k0 + c4 * 4];
            ushort4 o;
            o.x = f2bf(f.x); o.y = f2bf(f.y); o.z = f2bf(f.z); o.w = f2bf(f.w);
            *(ushort4*)&Vs[r * 72 + c4 * 4] = o;
        }
        __syncthreads();
#pragma unroll
        for (int kk = 0; kk < 2; ++kk) {
            bf16x8 a[4], b[4];
#pragma unroll
            for (int i = 0; i < 4; ++i)
                a[i] = *(const bf16x8*)&Ws[(rbase + 16 * i + lr) * 72 + kk * 32 + q * 8];
#pragma unroll
            for (int j = 0; j < 4; ++j)
                b[j] = *(const bf16x8*)&Vs[(cbase + 16 * j + lr) * 72 + kk * 32 + q * 8];
#pragma unroll
            for (int i = 0; i < 4; ++i)
#pragma unroll
                for (int j = 0; j < 4; ++j)
                    acc[i][j] = __builtin_amdgcn_mfma_f32_16x16x32_bf16(
                        a[i], b[j], acc[i][j], 0, 0, 0);
        }
    }
    // epilogue: rows = d, cols = m  -> vT[bt][d][m], bias on d (row)
    unsigned short* op = vT + (size_t)bt * N_ * D_;
#pragma unroll
    for (int i = 0; i < 4; ++i) {
        int row0 = rbase + 16 * i + q * 4;
#pragma unroll
        for (int j = 0; j < 4; ++j) {
            int col = m0 + cbase + 16 * j + lr;
#pragma unroll
            for (int e = 0; e < 4; ++e)
                op[(size_t)(row0 + e) * N_ + col] = f2bf(acc[i][j][e] + bv[row0 + e]);
        }
    }
}

// ---------------------------------------------------------------------------
// kC: out[b,t,n,d] = sum_m (mask ? score0 : -1e9) * v[b,t,m,d]  via bf16 MFMA
// (unchanged from round 3)
// ---------------------------------------------------------------------------
__global__ __launch_bounds__(256) void kC(const unsigned short* __restrict__ sc,
                                          const unsigned* __restrict__ mb,
                                          const unsigned short* __restrict__ vT,
                                          float* __restrict__ out) {
    int n0 = blockIdx.x * 128;
    int t = blockIdx.y, b = blockIdx.z;
    int tid = threadIdx.x;
    int wave = tid >> 6, lane = tid & 63;
    int q = lane >> 4, lr = lane & 15;
    int rbase = (wave & 1) * 64;
    int cbase = (wave >> 1) * 64;

    __shared__ unsigned short Ss[128 * 40];
    __shared__ unsigned short Vs[128 * 40];

    const unsigned short* scp = sc + (size_t)t * N_ * N_ + (size_t)n0 * N_;
    const unsigned short* vtp = vT + ((size_t)(b * T_ + t)) * N_ * D_;
    const unsigned* mbp = mb + ((size_t)b * N_ + n0) * 16;

    const unsigned short NEG = 0xCE6E;  // bf16(-1e9)

    f32x4 acc[4][4];
#pragma unroll
    for (int i = 0; i < 4; ++i)
#pragma unroll
        for (int j = 0; j < 4; ++j) acc[i][j] = (f32x4){0.f, 0.f, 0.f, 0.f};

    int sr = tid >> 1, sh = tid & 1;

    for (int kc = 0; kc < 16; ++kc) {
        int m0 = kc * 32;
        const unsigned short* g = scp + (size_t)sr * N_ + m0 + sh * 16;
        u16x8 s0 = *(const u16x8*)g;
        u16x8 s1 = *(const u16x8*)(g + 8);
        unsigned bits = mbp[sr * 16 + kc] >> (sh * 16);
        u16x8 o0, o1;
#pragma unroll
        for (int j = 0; j < 8; ++j) {
            o0[j] = ((bits >> j) & 1u) ? s0[j] : NEG;
            o1[j] = ((bits >> (j + 8)) & 1u) ? s1[j] : NEG;
        }
        *(u16x8*)&Ss[sr * 40 + sh * 16]     = o0;
        *(u16x8*)&Ss[sr * 40 + sh * 16 + 8] = o1;
#pragma unroll
        for (int i = 0; i < 2; ++i) {
            int lin = tid + i * 256;
            int d = lin >> 2, qq = lin & 3;
            *(u16x8*)&Vs[d * 40 + qq * 8] =
                *(const u16x8*)&vtp[(size_t)d * N_ + m0 + qq * 8];
        }
        __syncthreads();
        bf16x8 a[4], bfr[4];
#pragma unroll
        for (int i = 0; i < 4; ++i)
            a[i] = *(const bf16x8*)&Ss[(rbase + 16 * i + lr) * 40 + q * 8];
#pragma unroll
        for (int j = 0; j < 4; ++j)
            bfr[j] = *(const bf16x8*)&Vs[(cbase + 16 * j + lr) * 40 + q * 8];
#pragma unroll
        for (int i = 0; i < 4; ++i)
#pragma unroll
            for (int j = 0; j < 4; ++j)
                acc[i][j] = __builtin_amdgcn_mfma_f32_16x16x32_bf16(
                    a[i], bfr[j], acc[i][j], 0, 0, 0);
        __syncthreads();
    }

    float* ob = out + ((size_t)(b * T_ + t)) * N_ * D_;
#pragma unroll
    for (int i = 0; i < 4; ++i) {
#pragma unroll
        for (int j = 0; j < 4; ++j) {
            int row0 = n0 + rbase + 16 * i + q * 4;
            int col = cbase + 16 * j + lr;
#pragma unroll
            for (int e = 0; e < 4; ++e)
                ob[(size_t)(row0 + e) * D_ + col] = acc[i][j][e];
        }
    }
}

// ---------------------------------------------------------------------------
extern "C" void kernel_launch(void* const* d_in, const int* in_sizes, int n_in,
                              void* d_out, int out_size, void* d_ws, size_t ws_size,
                              hipStream_t stream) {
    const float* value = (const float*)d_in[0];
    const float* emb   = (const float*)d_in[1];
    const int*   mask  = (const int*)d_in[2];
    const float* Wqk   = (const float*)d_in[3];
    const float* bqk   = (const float*)d_in[4];
    const float* Wv    = (const float*)d_in[5];
    const float* bvv   = (const float*)d_in[6];
    float* out = (float*)d_out;

    float* ws = (float*)d_ws;
    float*          qkf  = ws;                                // 786432 f
    unsigned short* qb   = (unsigned short*)(ws + 786432);    // 786432 u16
    unsigned short* kNb  = (unsigned short*)(ws + 1179648);   // 786432 u16
    unsigned short* scb  = (unsigned short*)(ws + 1572864);   // 3145728 u16
    unsigned short* vtb  = (unsigned short*)(ws + 3145728);   // 12582912 u16
    unsigned short* WvTb = (unsigned short*)(ws + 9437184);   // 16384 u16
    unsigned*       mbp  = (unsigned*)(ws + 9445376);         // 131072 u32

    kA1<<<T_ * N_, 128, 0, stream>>>(emb, Wqk, bqk, qkf, qb);
    kA2n<<<48, 256, 0, stream>>>(qkf, kNb);
    kW<<<64, 256, 0, stream>>>(Wv, WvTb);
    kA3m<<<dim3(4, 4, T_), 256, 0, stream>>>(qb, kNb, scb);
    kM<<<512, 256, 0, stream>>>(mask, mbp);
    kBm<<<dim3(4, B_ * T_), 256, 0, stream>>>(value, WvTb, bvv, vtb);
    kC<<<dim3(4, T_, B_), 256, 0, stream>>>(scb, mbp, vtb, out);
}

// Round 5
// 167.109 us; speedup vs baseline: 2.1661x; 1.0660x over previous
//
#include <hip/hip_runtime.h>

#define B_ 16
#define T_ 12
#define N_ 512
#define D_ 128
#define E_ 32

typedef __attribute__((ext_vector_type(8))) unsigned short u16x8;
typedef __attribute__((ext_vector_type(8))) __bf16 bf16x8;
typedef __attribute__((ext_vector_type(4))) float f32x4;

static __device__ __forceinline__ unsigned short f2bf(float f) {
    unsigned u = __float_as_uint(f);
    unsigned r = (u + 0x7fffu + ((u >> 16) & 1u)) >> 16;
    return (unsigned short)r;
}

// ---------------------------------------------------------------------------
// kA1W: blocks [0,6144): qk = emb @ W_qk + b_qk (fp32) and q=softmax_D -> bf16
//       blocks [6144,6272): WvT[d][k] = bf16(Wv[k][d])
// ---------------------------------------------------------------------------
__global__ __launch_bounds__(128) void kA1W(const float* __restrict__ emb,
                                            const float* __restrict__ Wqk,
                                            const float* __restrict__ bqk,
                                            float* __restrict__ qk,
                                            unsigned short* __restrict__ qb,
                                            const float* __restrict__ Wv,
                                            unsigned short* __restrict__ WvT) {
    if (blockIdx.x >= 6144) {
        int i = (blockIdx.x - 6144) * 128 + threadIdx.x;  // 0..16383
        int d = i >> 7, k = i & 127;
        WvT[d * 128 + k] = f2bf(Wv[k * 128 + d]);
        return;
    }
    int tn = blockIdx.x;
    int d  = threadIdx.x;
    __shared__ float es[E_];
    if (d < E_) es[d] = emb[tn * E_ + d];
    __syncthreads();
    float acc = bqk[d];
#pragma unroll
    for (int e = 0; e < E_; ++e) acc = fmaf(es[e], Wqk[e * D_ + d], acc);
    qk[(size_t)tn * D_ + d] = acc;

    __shared__ float red[D_];
    red[d] = acc;
    __syncthreads();
#pragma unroll
    for (int s = 64; s > 0; s >>= 1) {
        if (d < s) red[d] = fmaxf(red[d], red[d + s]);
        __syncthreads();
    }
    float mx = red[0];
    __syncthreads();
    float ex = __expf(acc - mx);
    red[d] = ex;
    __syncthreads();
#pragma unroll
    for (int s = 64; s > 0; s >>= 1) {
        if (d < s) red[d] += red[d + s];
        __syncthreads();
    }
    qb[(size_t)tn * D_ + d] = f2bf(ex / red[0]);
}

// ---------------------------------------------------------------------------
// kA2n: kN[t,n,d] = softmax over n of qk[t,n,d], kept [n][d], bf16.
// grid (t=12 x dtile=16) = 192 blocks; 256 thr = 32(ni) x 8(dc); 16 n/thread.
// ---------------------------------------------------------------------------
__global__ __launch_bounds__(256) void kA2n(const float* __restrict__ qk,
                                            unsigned short* __restrict__ kN) {
    int t = blockIdx.x >> 4;
    int d0 = (blockIdx.x & 15) * 8;
    int tid = threadIdx.x;
    int dc = tid & 7, ni = tid >> 3;  // ni 0..31
    const float* base = qk + (size_t)t * N_ * D_ + d0 + dc;
    float vals[16];
    float mx = -1e30f;
#pragma unroll
    for (int j = 0; j < 16; ++j) {
        vals[j] = base[(size_t)(ni + 32 * j) * D_];
        mx = fmaxf(mx, vals[j]);
    }
    __shared__ float red[32][9];
    red[ni][dc] = mx;
    __syncthreads();
    if (tid < 8) {
        float m = red[0][tid];
#pragma unroll
        for (int r = 1; r < 32; ++r) m = fmaxf(m, red[r][tid]);
        red[0][tid] = m;
    }
    __syncthreads();
    mx = red[0][dc];
    float sum = 0.f;
#pragma unroll
    for (int j = 0; j < 16; ++j) {
        vals[j] = __expf(vals[j] - mx);
        sum += vals[j];
    }
    __syncthreads();
    red[ni][dc] = sum;
    __syncthreads();
    if (tid < 8) {
        float s = red[0][tid];
#pragma unroll
        for (int r = 1; r < 32; ++r) s += red[r][tid];
        red[0][tid] = s;
    }
    __syncthreads();
    float inv = 1.f / red[0][dc];
    unsigned short* op = kN + (size_t)t * N_ * D_ + d0 + dc;
#pragma unroll
    for (int j = 0; j < 16; ++j)
        op[(size_t)(ni + 32 * j) * D_] = f2bf(vals[j] * inv);
}

// ---------------------------------------------------------------------------
// kF: fused independent mid-stage. 256 thr.
//  blocks [0,192):    A3m: sc[t,n,m] = qb @ kN^T (bf16 MFMA, 128x128 tile)
//  blocks [192,960):  Bm:  vT[bt][d][m] = WvT @ value^T + bv (bf16 MFMA)
//  blocks [960,1472): M:   pack mask into bitmask words
// ---------------------------------------------------------------------------
__global__ __launch_bounds__(256) void kF(const unsigned short* __restrict__ qb,
                                          const unsigned short* __restrict__ kN,
                                          unsigned short* __restrict__ sc,
                                          const float* __restrict__ value,
                                          const unsigned short* __restrict__ WvT,
                                          const float* __restrict__ bv,
                                          unsigned short* __restrict__ vT,
                                          const int* __restrict__ mask,
                                          unsigned* __restrict__ mb) {
    __shared__ unsigned short shl[2][128 * 72];
    int bid = blockIdx.x;
    int tid = threadIdx.x;

    if (bid >= 960) {  // ---- kM ----
        int o = (bid - 960) * 256 + tid;  // 0..131071
        const int* mp = mask + (size_t)o * 32;
        unsigned bits = 0;
#pragma unroll
        for (int j = 0; j < 32; j += 4) {
            int4 m4 = *(const int4*)&mp[j];
            bits |= (m4.x ? 1u : 0u) << j;
            bits |= (m4.y ? 1u : 0u) << (j + 1);
            bits |= (m4.z ? 1u : 0u) << (j + 2);
            bits |= (m4.w ? 1u : 0u) << (j + 3);
        }
        mb[o] = bits;
        return;
    }

    int wave = tid >> 6, lane = tid & 63;
    int q = lane >> 4, lr = lane & 15;
    int rbase = (wave & 1) * 64, cbase = (wave >> 1) * 64;

    f32x4 acc[4][4];
#pragma unroll
    for (int i = 0; i < 4; ++i)
#pragma unroll
        for (int j = 0; j < 4; ++j) acc[i][j] = (f32x4){0.f, 0.f, 0.f, 0.f};

    if (bid < 192) {  // ---- kA3m ----
        int mt = bid & 3, nt = (bid >> 2) & 3, t = bid >> 4;
        int n0 = nt * 128, m0 = mt * 128;
        unsigned short* Qs = shl[0];
        unsigned short* Ks = shl[1];
        const unsigned short* qp = qb + (size_t)t * N_ * D_ + (size_t)n0 * D_;
        const unsigned short* kp = kN + (size_t)t * N_ * D_ + (size_t)m0 * D_;

        for (int c = 0; c < 2; ++c) {
            int k0 = c * 64;
            __syncthreads();
#pragma unroll
            for (int i = 0; i < 4; ++i) {
                int lin = tid + i * 256;
                int r = lin >> 3, seg = lin & 7;
                *(u16x8*)&Qs[r * 72 + seg * 8] =
                    *(const u16x8*)&qp[(size_t)r * D_ + k0 + seg * 8];
                *(u16x8*)&Ks[r * 72 + seg * 8] =
                    *(const u16x8*)&kp[(size_t)r * D_ + k0 + seg * 8];
            }
            __syncthreads();
#pragma unroll
            for (int kk = 0; kk < 2; ++kk) {
                bf16x8 a[4], b[4];
#pragma unroll
                for (int i = 0; i < 4; ++i)
                    a[i] = *(const bf16x8*)&Qs[(rbase + 16 * i + lr) * 72 + kk * 32 + q * 8];
#pragma unroll
                for (int j = 0; j < 4; ++j)
                    b[j] = *(const bf16x8*)&Ks[(cbase + 16 * j + lr) * 72 + kk * 32 + q * 8];
#pragma unroll
                for (int i = 0; i < 4; ++i)
#pragma unroll
                    for (int j = 0; j < 4; ++j)
                        acc[i][j] = __builtin_amdgcn_mfma_f32_16x16x32_bf16(
                            a[i], b[j], acc[i][j], 0, 0, 0);
            }
        }
        unsigned short* sp = sc + (size_t)t * N_ * N_;
#pragma unroll
        for (int i = 0; i < 4; ++i)
#pragma unroll
            for (int j = 0; j < 4; ++j) {
                int row0 = n0 + rbase + 16 * i + q * 4;
                int col = m0 + cbase + 16 * j + lr;
#pragma unroll
                for (int e = 0; e < 4; ++e)
                    sp[(size_t)(row0 + e) * N_ + col] = f2bf(acc[i][j][e]);
            }
        return;
    }

    // ---- kBm ----
    {
        int idx = bid - 192;
        int mt = idx & 3, bt = idx >> 2;
        int m0 = mt * 128;
        unsigned short* Ws = shl[0];
        unsigned short* Vs = shl[1];
        const float* vp = value + ((size_t)bt * N_ + m0) * D_;

        for (int c = 0; c < 2; ++c) {
            int k0 = c * 64;
            __syncthreads();
#pragma unroll
            for (int i = 0; i < 4; ++i) {
                int lin = tid + i * 256;
                int r = lin >> 3, seg = lin & 7;
                *(u16x8*)&Ws[r * 72 + seg * 8] =
                    *(const u16x8*)&WvT[r * 128 + k0 + seg * 8];
            }
#pragma unroll
            for (int i = 0; i < 8; ++i) {
                int lin = tid + i * 256;
                int r = lin >> 4, c4 = lin & 15;
                float4 f = *(const float4*)&vp[(size_t)r * D_ + k0 + c4 * 4];
                ushort4 o;
                o.x = f2bf(f.x); o.y = f2bf(f.y); o.z = f2bf(f.z); o.w = f2bf(f.w);
                *(ushort4*)&Vs[r * 72 + c4 * 4] = o;
            }
            __syncthreads();
#pragma unroll
            for (int kk = 0; kk < 2; ++kk) {
                bf16x8 a[4], b[4];
#pragma unroll
                for (int i = 0; i < 4; ++i)
                    a[i] = *(const bf16x8*)&Ws[(rbase + 16 * i + lr) * 72 + kk * 32 + q * 8];
#pragma unroll
                for (int j = 0; j < 4; ++j)
                    b[j] = *(const bf16x8*)&Vs[(cbase + 16 * j + lr) * 72 + kk * 32 + q * 8];
#pragma unroll
                for (int i = 0; i < 4; ++i)
#pragma unroll
                    for (int j = 0; j < 4; ++j)
                        acc[i][j] = __builtin_amdgcn_mfma_f32_16x16x32_bf16(
                            a[i], b[j], acc[i][j], 0, 0, 0);
            }
        }
        unsigned short* op = vT + (size_t)bt * N_ * D_;
#pragma unroll
        for (int i = 0; i < 4; ++i) {
            int row0 = rbase + 16 * i + q * 4;
#pragma unroll
            for (int j = 0; j < 4; ++j) {
                int col = m0 + cbase + 16 * j + lr;
#pragma unroll
                for (int e = 0; e < 4; ++e)
                    op[(size_t)(row0 + e) * N_ + col] = f2bf(acc[i][j][e] + bv[row0 + e]);
            }
        }
    }
}

// ---------------------------------------------------------------------------
// kC: out[b,t,n,d] = sum_m (mask ? score0 : -1e9) * v[b,t,m,d]  via bf16 MFMA
// tile 128(n) x 128(d), K=512 in 8 chunks of 64, register-prefetch pipeline.
// grid (4, T, B) = 768 blocks, 256 thr = 4 waves.
// ---------------------------------------------------------------------------
__global__ __launch_bounds__(256) void kC(const unsigned short* __restrict__ sc,
                                          const unsigned* __restrict__ mb,
                                          const unsigned short* __restrict__ vT,
                                          float* __restrict__ out) {
    int n0 = blockIdx.x * 128;
    int t = blockIdx.y, b = blockIdx.z;
    int tid = threadIdx.x;
    int wave = tid >> 6, lane = tid & 63;
    int q = lane >> 4, lr = lane & 15;
    int rbase = (wave & 1) * 64, cbase = (wave >> 1) * 64;

    __shared__ unsigned short Ss[128 * 72];
    __shared__ unsigned short Vs[128 * 72];

    const unsigned short* scp = sc + (size_t)t * N_ * N_ + (size_t)n0 * N_;
    const unsigned short* vtp = vT + ((size_t)(b * T_ + t)) * N_ * D_;  // [d][m]
    const unsigned* mbp = mb + ((size_t)b * N_ + n0) * 16;

    const unsigned short NEG = 0xCE6E;  // bf16(-1e9)

    f32x4 acc[4][4];
#pragma unroll
    for (int i = 0; i < 4; ++i)
#pragma unroll
        for (int j = 0; j < 4; ++j) acc[i][j] = (f32x4){0.f, 0.f, 0.f, 0.f};

    int sr = tid >> 1, sh2 = tid & 1;  // row 0..127, col-half (32 cols)
    const unsigned short* sg = scp + (size_t)sr * N_ + sh2 * 32;
    const unsigned short* vg = vtp + (size_t)sr * N_ + sh2 * 32;
    const unsigned* mwp = mbp + sr * 16 + sh2;

    u16x8 sreg[4], vreg[4];
    unsigned mw;
#pragma unroll
    for (int p = 0; p < 4; ++p) {
        sreg[p] = *(const u16x8*)(sg + p * 8);
        vreg[p] = *(const u16x8*)(vg + p * 8);
    }
    mw = mwp[0];

    for (int kc = 0; kc < 8; ++kc) {
        if (kc) __syncthreads();
        unsigned short* Sd = &Ss[sr * 72 + sh2 * 32];
        unsigned short* Vd = &Vs[sr * 72 + sh2 * 32];
#pragma unroll
        for (int p = 0; p < 4; ++p) {
            unsigned bits = mw >> (p * 8);
            u16x8 o;
#pragma unroll
            for (int j = 0; j < 8; ++j)
                o[j] = ((bits >> j) & 1u) ? sreg[p][j] : NEG;
            *(u16x8*)(Sd + p * 8) = o;
            *(u16x8*)(Vd + p * 8) = vreg[p];
        }
        __syncthreads();
        if (kc < 7) {
            int off = (kc + 1) * 64;
#pragma unroll
            for (int p = 0; p < 4; ++p) {
                sreg[p] = *(const u16x8*)(sg + off + p * 8);
                vreg[p] = *(const u16x8*)(vg + off + p * 8);
            }
            mw = mwp[(kc + 1) * 2];
        }
#pragma unroll
        for (int ks = 0; ks < 2; ++ks) {
            bf16x8 a[4], bfr[4];
#pragma unroll
            for (int i = 0; i < 4; ++i)
                a[i] = *(const bf16x8*)&Ss[(rbase + 16 * i + lr) * 72 + ks * 32 + q * 8];
#pragma unroll
            for (int j = 0; j < 4; ++j)
                bfr[j] = *(const bf16x8*)&Vs[(cbase + 16 * j + lr) * 72 + ks * 32 + q * 8];
#pragma unroll
            for (int i = 0; i < 4; ++i)
#pragma unroll
                for (int j = 0; j < 4; ++j)
                    acc[i][j] = __builtin_amdgcn_mfma_f32_16x16x32_bf16(
                        a[i], bfr[j], acc[i][j], 0, 0, 0);
        }
    }

    float* ob = out + ((size_t)(b * T_ + t)) * N_ * D_;
#pragma unroll
    for (int i = 0; i < 4; ++i) {
#pragma unroll
        for (int j = 0; j < 4; ++j) {
            int row0 = n0 + rbase + 16 * i + q * 4;
            int col = cbase + 16 * j + lr;
#pragma unroll
            for (int e = 0; e < 4; ++e)
                ob[(size_t)(row0 + e) * D_ + col] = acc[i][j][e];
        }
    }
}

// ---------------------------------------------------------------------------
extern "C" void kernel_launch(void* const* d_in, const int* in_sizes, int n_in,
                              void* d_out, int out_size, void* d_ws, size_t ws_size,
                              hipStream_t stream) {
    const float* value = (const float*)d_in[0];
    const float* emb   = (const float*)d_in[1];
    const int*   mask  = (const int*)d_in[2];
    const float* Wqk   = (const float*)d_in[3];
    const float* bqk   = (const float*)d_in[4];
    const float* Wv    = (const float*)d_in[5];
    const float* bvv   = (const float*)d_in[6];
    float* out = (float*)d_out;

    float* ws = (float*)d_ws;
    float*          qkf  = ws;                                // 786432 f
    unsigned short* qb   = (unsigned short*)(ws + 786432);    // 786432 u16
    unsigned short* kNb  = (unsigned short*)(ws + 1179648);   // 786432 u16
    unsigned short* scb  = (unsigned short*)(ws + 1572864);   // 3145728 u16
    unsigned short* vtb  = (unsigned short*)(ws + 3145728);   // 12582912 u16
    unsigned short* WvTb = (unsigned short*)(ws + 9437184);   // 16384 u16
    unsigned*       mbp  = (unsigned*)(ws + 9445376);         // 131072 u32

    kA1W<<<6272, 128, 0, stream>>>(emb, Wqk, bqk, qkf, qb, Wv, WvTb);
    kA2n<<<192, 256, 0, stream>>>(qkf, kNb);
    kF<<<1472, 256, 0, stream>>>(qb, kNb, scb, value, WvTb, bvv, vtb, mask, mbp);
    kC<<<dim3(4, T_, B_), 256, 0, stream>>>(scb, mbp, vtb, out);
}